// Round 1
// baseline (3327.452 us; speedup 1.0000x reference)
//
#include <hip/hip_runtime.h>
#include <math.h>

namespace {
constexpr int cB  = 8;
constexpr int cN  = 4096;
constexpr int cC  = 768;
constexpr int cH  = 12;
constexpr int cHD = 64;
constexpr int cM  = 32;
}

// C[M,N] = A[M,K] * B[N,K]^T + bias[N]   (both row-major, K contiguous)
__global__ __launch_bounds__(256)
void sgemm_nt(const float* __restrict__ A,
              const float* __restrict__ Bm,
              const float* __restrict__ bias,
              float* __restrict__ Cm,
              int Mdim, int Ndim, int K)
{
    constexpr int BM = 128, BN = 128, BK = 16;
    __shared__ float As[BK][BM + 4];
    __shared__ float Bs[BK][BN + 4];
    const int row0 = blockIdx.y * BM;
    const int col0 = blockIdx.x * BN;
    const int tid = threadIdx.x;
    const int tx = tid & 15, ty = tid >> 4;   // 16x16 threads, 8x8 micro-tile
    float acc[8][8] = {};
    for (int k0 = 0; k0 < K; k0 += BK) {
        for (int l = tid; l < BM * BK / 4; l += 256) {
            int r = l >> 2, c4 = (l & 3) << 2;
            float4 v = *reinterpret_cast<const float4*>(&A[(size_t)(row0 + r) * K + k0 + c4]);
            As[c4 + 0][r] = v.x; As[c4 + 1][r] = v.y; As[c4 + 2][r] = v.z; As[c4 + 3][r] = v.w;
        }
        for (int l = tid; l < BN * BK / 4; l += 256) {
            int r = l >> 2, c4 = (l & 3) << 2;
            float4 v = *reinterpret_cast<const float4*>(&Bm[(size_t)(col0 + r) * K + k0 + c4]);
            Bs[c4 + 0][r] = v.x; Bs[c4 + 1][r] = v.y; Bs[c4 + 2][r] = v.z; Bs[c4 + 3][r] = v.w;
        }
        __syncthreads();
        #pragma unroll
        for (int k = 0; k < BK; ++k) {
            float a[8], b[8];
            #pragma unroll
            for (int i = 0; i < 8; ++i) a[i] = As[k][ty * 8 + i];
            #pragma unroll
            for (int j = 0; j < 8; ++j) b[j] = Bs[k][tx * 8 + j];
            #pragma unroll
            for (int i = 0; i < 8; ++i)
                #pragma unroll
                for (int j = 0; j < 8; ++j)
                    acc[i][j] = fmaf(a[i], b[j], acc[i][j]);
        }
        __syncthreads();
    }
    #pragma unroll
    for (int i = 0; i < 8; ++i) {
        const int r = row0 + ty * 8 + i;
        #pragma unroll
        for (int j = 0; j < 8; ++j) {
            const int c = col0 + tx * 8 + j;
            Cm[(size_t)r * Ndim + c] = acc[i][j] + bias[c];
        }
    }
}

// phi[b,h,t,m] = exp(w[h,m,:].x  -  0.5*||x||^2) / sqrt(M),  x = k or q row
// kqv layout: [B, N, 3, H, HD];  which: 0 = k, 1 = q
__global__ __launch_bounds__(256)
void prm_exp_kernel(const float* __restrict__ kqv, const float* __restrict__ w,
                    float* __restrict__ phi, int which)
{
    const int bh = blockIdx.x;
    const int b = bh / cH, h = bh % cH;
    const int t0 = blockIdx.y * 64;
    __shared__ float wl[cM][cHD + 1];
    __shared__ float xl[64][cHD + 1];
    __shared__ float xd[64];
    const int tid = threadIdx.x;
    for (int l = tid; l < cM * cHD; l += 256) wl[l / cHD][l % cHD] = w[h * cM * cHD + l];
    for (int l = tid; l < 64 * cHD; l += 256) {
        int t = l >> 6, d = l & 63;
        xl[t][d] = kqv[(size_t)(b * cN + t0 + t) * (3 * cC) + which * cC + h * cHD + d];
    }
    __syncthreads();
    if (tid < 64) {
        float s = 0.f;
        #pragma unroll
        for (int d = 0; d < cHD; ++d) s = fmaf(xl[tid][d], xl[tid][d], s);
        xd[tid] = 0.5f * s;
    }
    __syncthreads();
    const float rsm = 0.17677669529663687f;  // 1/sqrt(32)
    #pragma unroll
    for (int it = 0; it < 8; ++it) {
        int id = it * 256 + tid;
        int t = id >> 5, m = id & 31;
        float s = 0.f;
        #pragma unroll
        for (int d = 0; d < cHD; ++d) s = fmaf(xl[t][d], wl[m][d], s);
        phi[((size_t)bh * cN + t0 + t) * cM + m] = __expf(s - xd[t]) * rsm;
    }
}

// kptv[b,h,d,m] = sum_t v[b,h,t,d] * kp[b,h,t,m];  kpsum[b,h,m] = sum_t kp[b,h,t,m]
// one block per (b,h) -> deterministic, no atomics
__global__ __launch_bounds__(256)
void kptv_kernel(const float* __restrict__ kqv, const float* __restrict__ kp,
                 float* __restrict__ kptv, float* __restrict__ kpsum)
{
    const int bh = blockIdx.x;
    const int b = bh / cH, h = bh % cH;
    __shared__ float vl[64][cHD + 1];
    __shared__ float kl[64][cM + 1];
    const int tid = threadIdx.x;
    const int d = tid >> 2, m4 = (tid & 3) * 8;
    float acc[8] = {};
    float ksum = 0.f;
    for (int t0 = 0; t0 < cN; t0 += 64) {
        for (int l = tid; l < 64 * cHD; l += 256) {
            int t = l >> 6, dd = l & 63;
            vl[t][dd] = kqv[(size_t)(b * cN + t0 + t) * (3 * cC) + 2 * cC + h * cHD + dd];
        }
        for (int l = tid; l < 64 * cM; l += 256) {
            int t = l >> 5, mm = l & 31;
            kl[t][mm] = kp[((size_t)bh * cN + t0 + t) * cM + mm];
        }
        __syncthreads();
        for (int t = 0; t < 64; ++t) {
            float a = vl[t][d];
            #pragma unroll
            for (int j = 0; j < 8; ++j) acc[j] = fmaf(a, kl[t][m4 + j], acc[j]);
        }
        if (tid < cM) {
            for (int t = 0; t < 64; ++t) ksum += kl[t][tid];
        }
        __syncthreads();
    }
    #pragma unroll
    for (int j = 0; j < 8; ++j) kptv[(size_t)bh * cHD * cM + d * cM + m4 + j] = acc[j];
    if (tid < cM) kpsum[bh * cM + tid] = ksum;
}

// y[b,t,h*64+d] = sum_m qp[b,h,t,m]*kptv[b,h,d,m] / (sum_m qp[b,h,t,m]*kpsum[b,h,m] + eps)
__global__ __launch_bounds__(256)
void pv_kernel(const float* __restrict__ qp, const float* __restrict__ kptv,
               const float* __restrict__ kpsum, float* __restrict__ y)
{
    const int bh = blockIdx.x;
    const int b = bh / cH, h = bh % cH;
    const int t0 = blockIdx.y * 32;
    __shared__ float kv[cHD][cM + 1];
    __shared__ float ks[cM];
    __shared__ float qs[4][cM];
    const int tid = threadIdx.x;
    for (int l = tid; l < cHD * cM; l += 256) kv[l >> 5][l & 31] = kptv[(size_t)bh * cHD * cM + l];
    if (tid < cM) ks[tid] = kpsum[bh * cM + tid];
    __syncthreads();
    const int dl = tid & 63, tq = tid >> 6;
    for (int it = 0; it < 8; ++it) {
        const int t = t0 + it * 4 + tq;
        if (dl < cM) qs[tq][dl] = qp[((size_t)bh * cN + t) * cM + dl];
        __syncthreads();
        float Dv = 0.f, yv = 0.f;
        #pragma unroll
        for (int m = 0; m < cM; ++m) {
            const float qv = qs[tq][m];
            Dv = fmaf(qv, ks[m], Dv);
            yv = fmaf(qv, kv[dl][m], yv);
        }
        y[(size_t)(b * cN + t) * cC + h * cHD + dl] = yv / (Dv + 1e-8f);
        __syncthreads();
    }
}

extern "C" void kernel_launch(void* const* d_in, const int* in_sizes, int n_in,
                              void* d_out, int out_size, void* d_ws, size_t ws_size,
                              hipStream_t stream)
{
    const float* x      = (const float*)d_in[0];
    const float* kqv_w  = (const float*)d_in[1];
    const float* kqv_b  = (const float*)d_in[2];
    const float* proj_w = (const float*)d_in[3];
    const float* proj_b = (const float*)d_in[4];
    const float* w      = (const float*)d_in[5];
    float* out = (float*)d_out;
    float* ws  = (float*)d_ws;

    // ws layout (floats): kqv 75,497,472 | kptv 196,608 | kpsum 3,072  => ~303 MB
    // y_att aliases kqv (kqv dead after kptv_kernel)
    // kp/qp live in d_out (dead before final proj GEMM overwrites it)
    float* kqv   = ws;
    float* kptv  = ws + 75497472;
    float* kpsum = kptv + 196608;
    float* y_att = ws;
    float* kp = out;                   // 12,582,912 floats
    float* qp = kp + 12582912;         // 12,582,912 floats (kp+qp == out_size exactly)

    dim3 blk(256);
    // kqv = x @ kqv_w^T + kqv_b : [32768,768] x [2304,768]^T
    sgemm_nt<<<dim3(2304 / 128, 32768 / 128), blk, 0, stream>>>(x, kqv_w, kqv_b, kqv, 32768, 2304, 768);
    // kp / qp
    prm_exp_kernel<<<dim3(cB * cH, cN / 64), blk, 0, stream>>>(kqv, w, kp, 0);
    prm_exp_kernel<<<dim3(cB * cH, cN / 64), blk, 0, stream>>>(kqv, w, qp, 1);
    // kptv + kpsum
    kptv_kernel<<<dim3(cB * cH), blk, 0, stream>>>(kqv, kp, kptv, kpsum);
    // normalized PV -> y_att [B,N,C]
    pv_kernel<<<dim3(cB * cH, cN / 32), blk, 0, stream>>>(qp, kptv, kpsum, y_att);
    // out = y_att @ proj_w^T + proj_b
    sgemm_nt<<<dim3(768 / 128, 32768 / 128), blk, 0, stream>>>(y_att, proj_w, proj_b, out, 32768, 768, 768);
}

// Round 2
// 1685.437 us; speedup vs baseline: 1.9742x; 1.9742x over previous
//
#include <hip/hip_runtime.h>
#include <math.h>

namespace {
constexpr int cB  = 8;
constexpr int cN  = 4096;
constexpr int cC  = 768;
constexpr int cH  = 12;
constexpr int cHD = 64;
constexpr int cM  = 32;
}

typedef __attribute__((ext_vector_type(8))) short bf16x8;
typedef __attribute__((ext_vector_type(4))) float f32x4;

__device__ __forceinline__ void async_copy16(const void* g, void* l) {
    __builtin_amdgcn_global_load_lds((const __attribute__((address_space(1))) void*)g,
                                     (__attribute__((address_space(3))) void*)l, 16, 0, 0);
}

__device__ __forceinline__ ushort f32_to_bf16_rne(float x) {
    unsigned int u = __float_as_uint(x);
    u += 0x7fffu + ((u >> 16) & 1u);
    return (ushort)(u >> 16);
}

// split fp32 -> bf16 hi (truncate) + bf16 lo (truncate of residual); a ~= hi+lo, rel err ~2^-16
__global__ __launch_bounds__(256)
void split_bf16(const float* __restrict__ in, ushort* __restrict__ hi,
                ushort* __restrict__ lo, int n4)
{
    int i = blockIdx.x * 256 + threadIdx.x;
    const int stride = gridDim.x * 256;
    for (; i < n4; i += stride) {
        float4 v = reinterpret_cast<const float4*>(in)[i];
        ushort4 h, l;
        {
            unsigned u = __float_as_uint(v.x); h.x = u >> 16;
            float r = v.x - __uint_as_float(u & 0xffff0000u); l.x = __float_as_uint(r) >> 16;
        }
        {
            unsigned u = __float_as_uint(v.y); h.y = u >> 16;
            float r = v.y - __uint_as_float(u & 0xffff0000u); l.y = __float_as_uint(r) >> 16;
        }
        {
            unsigned u = __float_as_uint(v.z); h.z = u >> 16;
            float r = v.z - __uint_as_float(u & 0xffff0000u); l.z = __float_as_uint(r) >> 16;
        }
        {
            unsigned u = __float_as_uint(v.w); h.w = u >> 16;
            float r = v.w - __uint_as_float(u & 0xffff0000u); l.w = __float_as_uint(r) >> 16;
        }
        reinterpret_cast<ushort4*>(hi)[i] = h;
        reinterpret_cast<ushort4*>(lo)[i] = l;
    }
}

// C[M,N] = sum_p Ap[M,K]*Bp[N,K]^T + bias   (bf16x3 split-precision MFMA GEMM)
// out_bf16=0 -> Cf fp32; out_bf16=1 -> Cb bf16 (RNE)
__global__ __launch_bounds__(256)
void gemm_bt_3(const ushort* __restrict__ Ah, const ushort* __restrict__ Al,
               const ushort* __restrict__ Bh, const ushort* __restrict__ Bl,
               const float* __restrict__ bias,
               float* __restrict__ Cf, ushort* __restrict__ Cb,
               int Ndim, int K, int out_bf16)
{
    __shared__ alignas(16) ushort As[128 * 32];
    __shared__ alignas(16) ushort Bs[128 * 32];
    const int tid = threadIdx.x;
    const int wave = tid >> 6, lane = tid & 63;
    const int row0 = blockIdx.y * 128, col0 = blockIdx.x * 128;
    const int wm = wave >> 1, wn = wave & 1;             // 64x64 wave tile
    const int sr = tid >> 2;                             // staging row within 64-group
    const int sk = (tid & 3) * 8;                        // staging k offset
    const int fr = lane & 15, fk = lane >> 4;            // fragment row / k-group
    f32x4 acc[4][4] = {};

    for (int pass = 0; pass < 3; ++pass) {
        const ushort* Ap = (pass < 2) ? Ah : Al;
        const ushort* Bp = (pass == 1) ? Bl : Bh;
        for (int k0 = 0; k0 < K; k0 += 32) {
            // stage A,B tiles (128x32 bf16 each) via async global->LDS, 16B/lane
            {
                const ushort* ga0 = &Ap[(size_t)(row0 + sr) * K + k0 + sk];
                const ushort* gb0 = &Bp[(size_t)(col0 + sr) * K + k0 + sk];
                async_copy16(ga0,            As + wave * 512);
                async_copy16(ga0 + 64 * K,   As + 2048 + wave * 512);
                async_copy16(gb0,            Bs + wave * 512);
                async_copy16(gb0 + 64 * K,   Bs + 2048 + wave * 512);
            }
            __syncthreads();   // compiler drains vmcnt(0) before barrier
            bf16x8 af[4], bfr[4];
            #pragma unroll
            for (int mi = 0; mi < 4; ++mi)
                af[mi] = *reinterpret_cast<const bf16x8*>(&As[(wm * 64 + mi * 16 + fr) * 32 + fk * 8]);
            #pragma unroll
            for (int ni = 0; ni < 4; ++ni)
                bfr[ni] = *reinterpret_cast<const bf16x8*>(&Bs[(wn * 64 + ni * 16 + fr) * 32 + fk * 8]);
            #pragma unroll
            for (int mi = 0; mi < 4; ++mi)
                #pragma unroll
                for (int ni = 0; ni < 4; ++ni)
                    acc[mi][ni] = __builtin_amdgcn_mfma_f32_16x16x32_bf16(af[mi], bfr[ni], acc[mi][ni], 0, 0, 0);
            __syncthreads();   // all waves done reading LDS before next stage
        }
    }

    const int rbase = row0 + wm * 64 + (lane >> 4) * 4;
    #pragma unroll
    for (int ni = 0; ni < 4; ++ni) {
        const int c = col0 + wn * 64 + ni * 16 + (lane & 15);
        const float bv = bias[c];
        #pragma unroll
        for (int mi = 0; mi < 4; ++mi) {
            const int r = rbase + mi * 16;
            #pragma unroll
            for (int j = 0; j < 4; ++j) {
                const float val = acc[mi][ni][j] + bv;
                if (out_bf16) Cb[(size_t)(r + j) * Ndim + c] = f32_to_bf16_rne(val);
                else          Cf[(size_t)(r + j) * Ndim + c] = val;
            }
        }
    }
}

// phi[b,h,t,m] = exp(w.x - 0.5||x||^2)/sqrt(M);  kq layout [B*N, 1536], k cols [0,768), q cols [768,1536)
__global__ __launch_bounds__(256)
void prm_exp_kernel(const float* __restrict__ kq, const float* __restrict__ w,
                    float* __restrict__ phi, int which)
{
    const int bh = blockIdx.x;
    const int b = bh / cH, h = bh % cH;
    const int t0 = blockIdx.y * 64;
    __shared__ float wl[cM][cHD + 1];
    __shared__ float xl[64][cHD + 1];
    __shared__ float xd[64];
    const int tid = threadIdx.x;
    for (int l = tid; l < cM * cHD; l += 256) wl[l / cHD][l % cHD] = w[h * cM * cHD + l];
    for (int l = tid; l < 64 * cHD; l += 256) {
        int t = l >> 6, d = l & 63;
        xl[t][d] = kq[(size_t)(b * cN + t0 + t) * 1536 + which * 768 + h * cHD + d];
    }
    __syncthreads();
    if (tid < 64) {
        float s = 0.f;
        #pragma unroll
        for (int d = 0; d < cHD; ++d) s = fmaf(xl[tid][d], xl[tid][d], s);
        xd[tid] = 0.5f * s;
    }
    __syncthreads();
    const float rsm = 0.17677669529663687f;  // 1/sqrt(32)
    #pragma unroll
    for (int it = 0; it < 8; ++it) {
        int id = it * 256 + tid;
        int t = id >> 5, m = id & 31;
        float s = 0.f;
        #pragma unroll
        for (int d = 0; d < cHD; ++d) s = fmaf(xl[t][d], wl[m][d], s);
        phi[((size_t)bh * cN + t0 + t) * cM + m] = __expf(s - xd[t]) * rsm;
    }
}

// partial kptv over t-chunk: kptv_p[chunk][bh][d][m], kpsum_p[chunk][bh][m]
__global__ __launch_bounds__(256)
void kptv_part(const ushort* __restrict__ vbf, const float* __restrict__ kp,
               float* __restrict__ kptv_p, float* __restrict__ kpsum_p)
{
    const int bh = blockIdx.x, chunk = blockIdx.y;
    const int b = bh / cH, h = bh % cH;
    __shared__ float vl[64][cHD + 1];
    __shared__ float kl[64][cM + 1];
    const int tid = threadIdx.x;
    const int d = tid >> 2, m4 = (tid & 3) * 8;
    float acc[8] = {};
    float ksum = 0.f;
    for (int t0 = chunk * 512; t0 < (chunk + 1) * 512; t0 += 64) {
        for (int l = tid; l < 64 * cHD; l += 256) {
            int t = l >> 6, dd = l & 63;
            vl[t][dd] = __uint_as_float((unsigned)vbf[(size_t)(b * cN + t0 + t) * cC + h * cHD + dd] << 16);
        }
        for (int l = tid; l < 64 * cM; l += 256) {
            int t = l >> 5, mm = l & 31;
            kl[t][mm] = kp[((size_t)bh * cN + t0 + t) * cM + mm];
        }
        __syncthreads();
        for (int t = 0; t < 64; ++t) {
            float a = vl[t][d];
            #pragma unroll
            for (int j = 0; j < 8; ++j) acc[j] = fmaf(a, kl[t][m4 + j], acc[j]);
        }
        if (tid < cM) {
            for (int t = 0; t < 64; ++t) ksum += kl[t][tid];
        }
        __syncthreads();
    }
    #pragma unroll
    for (int j = 0; j < 8; ++j)
        kptv_p[((size_t)chunk * 96 + bh) * (cHD * cM) + d * cM + m4 + j] = acc[j];
    if (tid < cM) kpsum_p[((size_t)chunk * 96 + bh) * cM + tid] = ksum;
}

__global__ __launch_bounds__(256)
void kptv_reduce(const float* __restrict__ kptv_p, const float* __restrict__ kpsum_p,
                 float* __restrict__ kptv, float* __restrict__ kpsum)
{
    const int bh = blockIdx.x, tid = threadIdx.x;
    for (int l = tid; l < cHD * cM; l += 256) {
        float s = 0.f;
        #pragma unroll
        for (int c = 0; c < 8; ++c) s += kptv_p[((size_t)c * 96 + bh) * (cHD * cM) + l];
        kptv[(size_t)bh * (cHD * cM) + l] = s;
    }
    if (tid < cM) {
        float s = 0.f;
        #pragma unroll
        for (int c = 0; c < 8; ++c) s += kpsum_p[((size_t)c * 96 + bh) * cM + tid];
        kpsum[bh * cM + tid] = s;
    }
}

__global__ __launch_bounds__(256)
void pv_kernel(const float* __restrict__ qp, const float* __restrict__ kptv,
               const float* __restrict__ kpsum, float* __restrict__ y)
{
    const int bh = blockIdx.x;
    const int b = bh / cH, h = bh % cH;
    const int t0 = blockIdx.y * 32;
    __shared__ float kv[cHD][cM + 1];
    __shared__ float ks[cM];
    __shared__ float qs[4][cM];
    const int tid = threadIdx.x;
    for (int l = tid; l < cHD * cM; l += 256) kv[l >> 5][l & 31] = kptv[(size_t)bh * cHD * cM + l];
    if (tid < cM) ks[tid] = kpsum[bh * cM + tid];
    __syncthreads();
    const int dl = tid & 63, tq = tid >> 6;
    for (int it = 0; it < 8; ++it) {
        const int t = t0 + it * 4 + tq;
        if (dl < cM) qs[tq][dl] = qp[((size_t)bh * cN + t) * cM + dl];
        __syncthreads();
        float Dv = 0.f, yv = 0.f;
        #pragma unroll
        for (int m = 0; m < cM; ++m) {
            const float qv = qs[tq][m];
            Dv = fmaf(qv, ks[m], Dv);
            yv = fmaf(qv, kv[dl][m], yv);
        }
        y[(size_t)(b * cN + t) * cC + h * cHD + dl] = yv / (Dv + 1e-8f);
        __syncthreads();
    }
}

extern "C" void kernel_launch(void* const* d_in, const int* in_sizes, int n_in,
                              void* d_out, int out_size, void* d_ws, size_t ws_size,
                              hipStream_t stream)
{
    const float* x      = (const float*)d_in[0];
    const float* kqv_w  = (const float*)d_in[1];
    const float* kqv_b  = (const float*)d_in[2];
    const float* proj_w = (const float*)d_in[3];
    const float* proj_b = (const float*)d_in[4];
    const float* w      = (const float*)d_in[5];

    char* wsb = (char*)d_ws;
    // ws layout (bytes):
    float*  kq      = (float*)(wsb);                    // [32768,1536] fp32 = 201,326,592 B
    float*  y_att   = (float*)(wsb);                    // aliases kq[0..100,663,296) after kq dead
    ushort* yh      = (ushort*)(wsb + 100663296);       // 50,331,648 B (kq region 2nd half)
    ushort* yl      = (ushort*)(wsb + 150994944);       // 50,331,648 B
    ushort* vbf     = (ushort*)(wsb + 201326592);       // [32768,768] bf16 = 50,331,648 B
    ushort* wh      = (ushort*)(wsb + 251658240);       // kqv_w hi 3,538,944 B
    ushort* wl_     = (ushort*)(wsb + 255197184);       // kqv_w lo
    ushort* pwh     = (ushort*)(wsb + 258736128);       // proj_w hi 1,179,648 B
    ushort* pwl     = (ushort*)(wsb + 259915776);       // proj_w lo
    float*  kptv_p  = (float*)(wsb + 261095424);        // 8*96*2048*4 = 6,291,456 B
    float*  kpsum_p = (float*)(wsb + 267386880);        // 98,304 B
    float*  kptvB   = (float*)(wsb + 267485184);        // 786,432 B
    float*  kpsumB  = (float*)(wsb + 268271616);        // 12,288 B  (total ~268 MB)

    // d_out staging: x hi/lo planes, later kp/qp, finally the real output
    ushort* xh = (ushort*)d_out;                        // 50,331,648 B
    ushort* xl = (ushort*)((char*)d_out + 50331648);
    float*  kp = (float*)d_out;                         // 12,582,912 floats
    float*  qp = kp + 12582912;
    float*  out = (float*)d_out;

    dim3 blk(256);
    // 1. split x and weights into bf16 hi/lo planes
    split_bf16<<<2048, blk, 0, stream>>>(x, xh, xl, 25165824 / 4);
    split_bf16<<<1728, blk, 0, stream>>>(kqv_w, wh, wl_, 1769472 / 4);
    split_bf16<<<576, blk, 0, stream>>>(proj_w, pwh, pwl, 589824 / 4);
    // 2. kq = x @ kqv_w[0:1536]^T  (fp32 out, feeds exp)
    gemm_bt_3<<<dim3(12, 256), blk, 0, stream>>>(xh, xl, wh, wl_, kqv_b, kq, nullptr, 1536, 768, 0);
    // 3. v = x @ kqv_w[1536:2304]^T  (bf16 out)
    gemm_bt_3<<<dim3(6, 256), blk, 0, stream>>>(xh, xl, wh + (size_t)1536 * 768, wl_ + (size_t)1536 * 768,
                                                kqv_b + 1536, nullptr, vbf, 768, 768, 1);
    // 4. kp / qp  (overwrite xh/xl in d_out)
    prm_exp_kernel<<<dim3(cB * cH, cN / 64), blk, 0, stream>>>(kq, w, kp, 0);
    prm_exp_kernel<<<dim3(cB * cH, cN / 64), blk, 0, stream>>>(kq, w, qp, 1);
    // 5. kptv partials + reduce
    kptv_part<<<dim3(cB * cH, 8), blk, 0, stream>>>(vbf, kp, kptv_p, kpsum_p);
    kptv_reduce<<<dim3(cB * cH), blk, 0, stream>>>(kptv_p, kpsum_p, kptvB, kpsumB);
    // 6. normalized PV -> y_att (overwrites kq 1st half; kq dead)
    pv_kernel<<<dim3(cB * cH, cN / 32), blk, 0, stream>>>(qp, kptvB, kpsumB, y_att);
    // 7. split y_att -> bf16 planes (into kq 2nd half)
    split_bf16<<<2048, blk, 0, stream>>>(y_att, yh, yl, 25165824 / 4);
    // 8. out = y_att @ proj_w^T + proj_b
    gemm_bt_3<<<dim3(6, 256), blk, 0, stream>>>(yh, yl, pwh, pwl, proj_b, out, nullptr, 768, 768, 0);
}

// Round 3
// 831.224 us; speedup vs baseline: 4.0031x; 2.0277x over previous
//
#include <hip/hip_runtime.h>
#include <math.h>

namespace {
constexpr int cB  = 8;
constexpr int cN  = 4096;
constexpr int cC  = 768;
constexpr int cH  = 12;
constexpr int cHD = 64;
constexpr int cM  = 32;
}

typedef __attribute__((ext_vector_type(8))) short bf16x8;
typedef __attribute__((ext_vector_type(4))) float f32x4;

__device__ __forceinline__ void async_copy16(const void* g, void* l) {
    __builtin_amdgcn_global_load_lds((const __attribute__((address_space(1))) void*)g,
                                     (__attribute__((address_space(3))) void*)l, 16, 0, 0);
}

__device__ __forceinline__ ushort f32_to_bf16_rne(float x) {
    unsigned int u = __float_as_uint(x);
    u += 0x7fffu + ((u >> 16) & 1u);
    return (ushort)(u >> 16);
}

__device__ __forceinline__ float bf16_to_f32(ushort u) {
    return __uint_as_float(((unsigned)u) << 16);
}

__device__ __forceinline__ void split2(float f, ushort& h, ushort& l) {
    unsigned u = __float_as_uint(f);
    h = (ushort)(u >> 16);
    float r = f - __uint_as_float(u & 0xffff0000u);
    l = (ushort)(__float_as_uint(r) >> 16);
}

// split fp32 -> bf16 hi (truncate) + bf16 lo (truncate of residual)
__global__ __launch_bounds__(256)
void split_bf16(const float* __restrict__ in, ushort* __restrict__ hi,
                ushort* __restrict__ lo, int n4)
{
    int i = blockIdx.x * 256 + threadIdx.x;
    const int stride = gridDim.x * 256;
    for (; i < n4; i += stride) {
        float4 v = reinterpret_cast<const float4*>(in)[i];
        ushort4 h, l;
        split2(v.x, h.x, l.x);
        split2(v.y, h.y, l.y);
        split2(v.z, h.z, l.z);
        split2(v.w, h.w, l.w);
        reinterpret_cast<ushort4*>(hi)[i] = h;
        reinterpret_cast<ushort4*>(lo)[i] = l;
    }
}

// C[M,N] = sum_p Ap[M,K]*Bp[N,K]^T + bias   (bf16x3 split-precision MFMA GEMM)
// mode 0: Cf fp32 linear [M,Ndim]; mode 2: Cb bf16, v-permuted [b,h,t,d] layout
__global__ __launch_bounds__(256)
void gemm_bt_3(const ushort* __restrict__ Ah, const ushort* __restrict__ Al,
               const ushort* __restrict__ Bh, const ushort* __restrict__ Bl,
               const float* __restrict__ bias,
               float* __restrict__ Cf, ushort* __restrict__ Cb,
               int Ndim, int K, int mode)
{
    __shared__ alignas(16) ushort As[128 * 32];
    __shared__ alignas(16) ushort Bs[128 * 32];
    const int tid = threadIdx.x;
    const int wave = tid >> 6, lane = tid & 63;
    const int row0 = blockIdx.y * 128, col0 = blockIdx.x * 128;
    const int wm = wave >> 1, wn = wave & 1;
    const int sr = tid >> 2;
    const int sk = (tid & 3) * 8;
    const int fr = lane & 15, fk = lane >> 4;
    f32x4 acc[4][4] = {};

    for (int pass = 0; pass < 3; ++pass) {
        const ushort* Ap = (pass < 2) ? Ah : Al;
        const ushort* Bp = (pass == 1) ? Bl : Bh;
        for (int k0 = 0; k0 < K; k0 += 32) {
            {
                const ushort* ga0 = &Ap[(size_t)(row0 + sr) * K + k0 + sk];
                const ushort* gb0 = &Bp[(size_t)(col0 + sr) * K + k0 + sk];
                async_copy16(ga0,            As + wave * 512);
                async_copy16(ga0 + 64 * K,   As + 2048 + wave * 512);
                async_copy16(gb0,            Bs + wave * 512);
                async_copy16(gb0 + 64 * K,   Bs + 2048 + wave * 512);
            }
            __syncthreads();
            bf16x8 af[4], bfr[4];
            #pragma unroll
            for (int mi = 0; mi < 4; ++mi)
                af[mi] = *reinterpret_cast<const bf16x8*>(&As[(wm * 64 + mi * 16 + fr) * 32 + fk * 8]);
            #pragma unroll
            for (int ni = 0; ni < 4; ++ni)
                bfr[ni] = *reinterpret_cast<const bf16x8*>(&Bs[(wn * 64 + ni * 16 + fr) * 32 + fk * 8]);
            #pragma unroll
            for (int mi = 0; mi < 4; ++mi)
                #pragma unroll
                for (int ni = 0; ni < 4; ++ni)
                    acc[mi][ni] = __builtin_amdgcn_mfma_f32_16x16x32_bf16(af[mi], bfr[ni], acc[mi][ni], 0, 0, 0);
            __syncthreads();
        }
    }

    const int rbase = row0 + wm * 64 + (lane >> 4) * 4;
    #pragma unroll
    for (int ni = 0; ni < 4; ++ni) {
        const int c = col0 + wn * 64 + ni * 16 + (lane & 15);
        const float bv = bias[c];
        #pragma unroll
        for (int mi = 0; mi < 4; ++mi) {
            const int r = rbase + mi * 16;
            #pragma unroll
            for (int j = 0; j < 4; ++j) {
                const float val = acc[mi][ni][j] + bv;
                const int row = r + j;
                if (mode == 0) {
                    Cf[(size_t)row * Ndim + c] = val;
                } else {
                    const int b = row >> 12, t = row & 4095;
                    const int h = c >> 6, d = c & 63;
                    Cb[(((size_t)(b * cH + h) * cN + t) << 6) + d] = f32_to_bf16_rne(val);
                }
            }
        }
    }
}

// Performer feature map via register-direct MFMA. One wave per (bh, 64-t block).
// phi[bh,t,m] = exp((k.w[h,m]) - 0.5||k||^2)/sqrt(M), bf16 out.
// k read fp32 from kq [32768,1536] at col_off; w pre-split bf16 hi/lo.
__global__ __launch_bounds__(64)
void prm_exp_mfma(const float* __restrict__ kq, const ushort* __restrict__ wh,
                  const ushort* __restrict__ wl, ushort* __restrict__ phi,
                  float* __restrict__ kpsum_p, int col_off, int do_sum)
{
    const int bh = blockIdx.x, tblk = blockIdx.y;
    const int b = bh / cH, h = bh % cH;
    const int t0 = tblk * 64;
    const int lane = threadIdx.x;
    const int fr = lane & 15, fk = lane >> 4;

    bf16x8 Bh2[2][2], Bl2[2][2];
    #pragma unroll
    for (int mf = 0; mf < 2; ++mf)
        #pragma unroll
        for (int kc = 0; kc < 2; ++kc) {
            size_t off = (size_t)(h * 32 + mf * 16 + fr) * 64 + kc * 32 + fk * 8;
            Bh2[mf][kc] = *reinterpret_cast<const bf16x8*>(&wh[off]);
            Bl2[mf][kc] = *reinterpret_cast<const bf16x8*>(&wl[off]);
        }

    f32x4 acc[4][2] = {};
    float xdv4[4];
    #pragma unroll
    for (int tf = 0; tf < 4; ++tf) {
        const float* krow = &kq[(size_t)(b * cN + t0 + tf * 16 + fr) * 1536 + col_off + h * 64];
        float4 f0 = *reinterpret_cast<const float4*>(&krow[fk * 8]);
        float4 f1 = *reinterpret_cast<const float4*>(&krow[fk * 8 + 4]);
        float4 f2 = *reinterpret_cast<const float4*>(&krow[32 + fk * 8]);
        float4 f3 = *reinterpret_cast<const float4*>(&krow[32 + fk * 8 + 4]);
        float xs = f0.x*f0.x + f0.y*f0.y + f0.z*f0.z + f0.w*f0.w
                 + f1.x*f1.x + f1.y*f1.y + f1.z*f1.z + f1.w*f1.w
                 + f2.x*f2.x + f2.y*f2.y + f2.z*f2.z + f2.w*f2.w
                 + f3.x*f3.x + f3.y*f3.y + f3.z*f3.z + f3.w*f3.w;
        xs += __shfl_xor(xs, 16);
        xs += __shfl_xor(xs, 32);
        xdv4[tf] = 0.5f * xs;
        bf16x8 Ah2[2], Al2[2];
        {
            float fa[8] = {f0.x,f0.y,f0.z,f0.w,f1.x,f1.y,f1.z,f1.w};
            float fb[8] = {f2.x,f2.y,f2.z,f2.w,f3.x,f3.y,f3.z,f3.w};
            #pragma unroll
            for (int j = 0; j < 8; ++j) {
                ushort hh, ll;
                split2(fa[j], hh, ll); Ah2[0][j] = (short)hh; Al2[0][j] = (short)ll;
                split2(fb[j], hh, ll); Ah2[1][j] = (short)hh; Al2[1][j] = (short)ll;
            }
        }
        #pragma unroll
        for (int kc = 0; kc < 2; ++kc)
            #pragma unroll
            for (int mf = 0; mf < 2; ++mf) {
                acc[tf][mf] = __builtin_amdgcn_mfma_f32_16x16x32_bf16(Ah2[kc], Bh2[mf][kc], acc[tf][mf], 0, 0, 0);
                acc[tf][mf] = __builtin_amdgcn_mfma_f32_16x16x32_bf16(Ah2[kc], Bl2[mf][kc], acc[tf][mf], 0, 0, 0);
                acc[tf][mf] = __builtin_amdgcn_mfma_f32_16x16x32_bf16(Al2[kc], Bh2[mf][kc], acc[tf][mf], 0, 0, 0);
            }
    }

    const float rsm = 0.17677669529663687f;  // 1/sqrt(32)
    float sm0 = 0.f, sm1 = 0.f;
    #pragma unroll
    for (int tf = 0; tf < 4; ++tf) {
        #pragma unroll
        for (int j = 0; j < 4; ++j) {
            const int rloc = (lane >> 4) * 4 + j;
            const float xdv = __shfl(xdv4[tf], (lane & 48) | rloc);
            const int t = t0 + tf * 16 + rloc;
            float e0 = __expf(acc[tf][0][j] - xdv) * rsm;
            float e1 = __expf(acc[tf][1][j] - xdv) * rsm;
            phi[((size_t)bh * cN + t) * cM + fr]      = f32_to_bf16_rne(e0);
            phi[((size_t)bh * cN + t) * cM + 16 + fr] = f32_to_bf16_rne(e1);
            sm0 += e0; sm1 += e1;
        }
    }
    if (do_sum) {
        sm0 += __shfl_xor(sm0, 16); sm0 += __shfl_xor(sm0, 32);
        sm1 += __shfl_xor(sm1, 16); sm1 += __shfl_xor(sm1, 32);
        if (lane < 16) {
            kpsum_p[((size_t)bh * 64 + tblk) * cM + lane]      = sm0;
            kpsum_p[((size_t)bh * 64 + tblk) * cM + 16 + lane] = sm1;
        }
    }
}

// kptv partials: kptv_p[c][bh][d][m] over 32-t slices; c = chunk*2+half, 16 total
__global__ __launch_bounds__(256, 4)
void kptv_part(const ushort* __restrict__ vbf, const ushort* __restrict__ kp,
               float* __restrict__ kptv_p)
{
    const int bh = blockIdx.x, chunk = blockIdx.y;
    __shared__ float vl[64][68];
    __shared__ float kl[64][36];
    const int tid = threadIdx.x;
    const int half = tid >> 7;
    const int dg = (tid >> 3) & 15;
    const int mg = tid & 7;
    float acc[4][4] = {};
    for (int tile = 0; tile < 8; ++tile) {
        const int tb = chunk * 512 + tile * 64;
        #pragma unroll
        for (int i = 0; i < 2; ++i) {
            int idx = i * 256 + tid;
            int row = idx >> 3, seg = idx & 7;
            bf16x8 vv = *reinterpret_cast<const bf16x8*>(&vbf[((size_t)bh * cN + tb + row) * 64 + seg * 8]);
            float4 lo4 = make_float4(bf16_to_f32((ushort)vv[0]), bf16_to_f32((ushort)vv[1]),
                                     bf16_to_f32((ushort)vv[2]), bf16_to_f32((ushort)vv[3]));
            float4 hi4 = make_float4(bf16_to_f32((ushort)vv[4]), bf16_to_f32((ushort)vv[5]),
                                     bf16_to_f32((ushort)vv[6]), bf16_to_f32((ushort)vv[7]));
            *reinterpret_cast<float4*>(&vl[row][seg * 8])     = lo4;
            *reinterpret_cast<float4*>(&vl[row][seg * 8 + 4]) = hi4;
        }
        {
            int row = tid >> 2, seg = tid & 3;
            bf16x8 vv = *reinterpret_cast<const bf16x8*>(&kp[((size_t)bh * cN + tb + row) * 32 + seg * 8]);
            float4 lo4 = make_float4(bf16_to_f32((ushort)vv[0]), bf16_to_f32((ushort)vv[1]),
                                     bf16_to_f32((ushort)vv[2]), bf16_to_f32((ushort)vv[3]));
            float4 hi4 = make_float4(bf16_to_f32((ushort)vv[4]), bf16_to_f32((ushort)vv[5]),
                                     bf16_to_f32((ushort)vv[6]), bf16_to_f32((ushort)vv[7]));
            *reinterpret_cast<float4*>(&kl[row][seg * 8])     = lo4;
            *reinterpret_cast<float4*>(&kl[row][seg * 8 + 4]) = hi4;
        }
        __syncthreads();
        for (int t = 0; t < 32; ++t) {
            const int tt = half * 32 + t;
            float4 av = *reinterpret_cast<const float4*>(&vl[tt][dg * 4]);
            float4 bv = *reinterpret_cast<const float4*>(&kl[tt][mg * 4]);
            float a4[4] = {av.x, av.y, av.z, av.w};
            float b4[4] = {bv.x, bv.y, bv.z, bv.w};
            #pragma unroll
            for (int i = 0; i < 4; ++i)
                #pragma unroll
                for (int j = 0; j < 4; ++j)
                    acc[i][j] = fmaf(a4[i], b4[j], acc[i][j]);
        }
        __syncthreads();
    }
    float* outp = &kptv_p[(((size_t)chunk * 2 + half) * 96 + bh) * 2048];
    #pragma unroll
    for (int i = 0; i < 4; ++i)
        *reinterpret_cast<float4*>(&outp[(dg * 4 + i) * 32 + mg * 4]) =
            make_float4(acc[i][0], acc[i][1], acc[i][2], acc[i][3]);
}

// reduce partials -> kptvx bf16 [bh][80][32]: rows 0..63 kptv, row 64 kpsum, 65..79 zero
__global__ __launch_bounds__(256)
void kptv_reduce(const float* __restrict__ kptv_p, const float* __restrict__ kpsum_p,
                 ushort* __restrict__ kptvx)
{
    const int bh = blockIdx.x, tid = threadIdx.x;
    for (int l = tid; l < 2048; l += 256) {
        float s = 0.f;
        #pragma unroll
        for (int c = 0; c < 16; ++c) s += kptv_p[((size_t)c * 96 + bh) * 2048 + l];
        kptvx[(size_t)bh * 2560 + l] = f32_to_bf16_rne(s);
    }
    if (tid < 32) {
        float s = 0.f;
        #pragma unroll
        for (int c = 0; c < 64; ++c) s += kpsum_p[((size_t)bh * 64 + c) * cM + tid];
        kptvx[(size_t)bh * 2560 + 64 * 32 + tid] = f32_to_bf16_rne(s);
    }
    for (int l = tid; l < 480; l += 256)
        kptvx[(size_t)bh * 2560 + 65 * 32 + l] = 0;
}

// y = (qp . kptv) / (qp . kpsum + eps) via one MFMA pass (D appended as B-row 64)
// writes y pre-split to bf16 hi/lo planes for the proj GEMM
__global__ __launch_bounds__(64)
void pv_mfma(const ushort* __restrict__ qp, const ushort* __restrict__ kptvx,
             ushort* __restrict__ yh, ushort* __restrict__ yl)
{
    const int bh = blockIdx.x, tblk = blockIdx.y;
    const int b = bh / cH, h = bh % cH;
    const int t0 = tblk * 64;
    const int lane = threadIdx.x;
    const int fr = lane & 15, fk = lane >> 4;
    bf16x8 Bf[5];
    #pragma unroll
    for (int nf = 0; nf < 5; ++nf)
        Bf[nf] = *reinterpret_cast<const bf16x8*>(&kptvx[(size_t)bh * 2560 + (nf * 16 + fr) * 32 + fk * 8]);
    f32x4 acc[4][5] = {};
    #pragma unroll
    for (int tf = 0; tf < 4; ++tf) {
        bf16x8 Af = *reinterpret_cast<const bf16x8*>(&qp[((size_t)bh * cN + t0 + tf * 16 + fr) * cM + fk * 8]);
        #pragma unroll
        for (int nf = 0; nf < 5; ++nf)
            acc[tf][nf] = __builtin_amdgcn_mfma_f32_16x16x32_bf16(Af, Bf[nf], acc[tf][nf], 0, 0, 0);
    }
    #pragma unroll
    for (int tf = 0; tf < 4; ++tf) {
        #pragma unroll
        for (int j = 0; j < 4; ++j) {
            const int rloc = (lane >> 4) * 4 + j;
            const int t = t0 + tf * 16 + rloc;
            const float Dv = __shfl(acc[tf][4][j], lane & 48) + 1e-8f;
            const float rD = 1.0f / Dv;
            #pragma unroll
            for (int nf = 0; nf < 4; ++nf) {
                float yv = acc[tf][nf][j] * rD;
                ushort hh, ll; split2(yv, hh, ll);
                size_t oa = (size_t)(b * cN + t) * cC + h * 64 + nf * 16 + fr;
                yh[oa] = hh; yl[oa] = ll;
            }
        }
    }
}

extern "C" void kernel_launch(void* const* d_in, const int* in_sizes, int n_in,
                              void* d_out, int out_size, void* d_ws, size_t ws_size,
                              hipStream_t stream)
{
    const float* x      = (const float*)d_in[0];
    const float* kqv_w  = (const float*)d_in[1];
    const float* kqv_b  = (const float*)d_in[2];
    const float* proj_w = (const float*)d_in[3];
    const float* proj_b = (const float*)d_in[4];
    const float* w      = (const float*)d_in[5];

    char* wsb = (char*)d_ws;
    float*  kq   = (float*)(wsb);                  // [32768,1536] fp32, 201,326,592 B
    ushort* yh   = (ushort*)(wsb);                 // aliases kq after dead
    ushort* yl   = (ushort*)(wsb + 50331648);
    ushort* vbf  = (ushort*)(wsb + 201326592);     // [96][4096][64] bf16
    ushort* wh   = (ushort*)(wsb + 251658240);     // kqv_w hi
    ushort* wl_  = (ushort*)(wsb + 255197184);     // kqv_w lo
    ushort* pwh  = (ushort*)(wsb + 258736128);     // proj_w hi
    ushort* pwl  = (ushort*)(wsb + 259915776);     // proj_w lo
    ushort* whb  = (ushort*)(wsb + 261095424);     // w hi (bf16)
    ushort* wlb  = (ushort*)(wsb + 261144576);     // w lo

    char* ob = (char*)d_out;
    ushort* xh      = (ushort*)ob;                 // x hi plane
    ushort* xl      = (ushort*)(ob + 50331648);    // x lo plane
    ushort* kp      = (ushort*)ob;                 // [96][4096][32] bf16 (after xh dead)
    ushort* qp      = (ushort*)(ob + 25165824);
    float*  kptv_p  = (float*)(ob + 50331648);     // [16][96][2048] fp32 (after xl dead)
    float*  kpsum_p = (float*)(ob + 62914560);     // [96][64][32] fp32
    ushort* kptvx   = (ushort*)(ob + 63700992);    // [96][80][32] bf16
    float*  out     = (float*)d_out;

    dim3 blk(256);
    // splits
    split_bf16<<<2048, blk, 0, stream>>>(x, xh, xl, 25165824 / 4);
    split_bf16<<<1728, blk, 0, stream>>>(kqv_w, wh, wl_, 1769472 / 4);
    split_bf16<<<576, blk, 0, stream>>>(proj_w, pwh, pwl, 589824 / 4);
    split_bf16<<<24, blk, 0, stream>>>(w, whb, wlb, 24576 / 4);
    // kq = x @ kqv_w[0:1536]^T  (fp32)
    gemm_bt_3<<<dim3(12, 256), blk, 0, stream>>>(xh, xl, wh, wl_, kqv_b, kq, nullptr, 1536, 768, 0);
    // v  = x @ kqv_w[1536:2304]^T  (bf16, [b,h,t,d] layout)
    gemm_bt_3<<<dim3(6, 256), blk, 0, stream>>>(xh, xl, wh + (size_t)1536 * 768, wl_ + (size_t)1536 * 768,
                                                kqv_b + 1536, nullptr, vbf, 768, 768, 2);
    // feature maps (xh/xl dead now; kp/qp overwrite them)
    prm_exp_mfma<<<dim3(96, 64), dim3(64), 0, stream>>>(kq, whb, wlb, kp, kpsum_p, 0, 1);
    prm_exp_mfma<<<dim3(96, 64), dim3(64), 0, stream>>>(kq, whb, wlb, qp, nullptr, 768, 0);
    // kptv partials + reduce (kq dead after prm_exp)
    kptv_part<<<dim3(96, 8), blk, 0, stream>>>(vbf, kp, kptv_p);
    kptv_reduce<<<dim3(96), blk, 0, stream>>>(kptv_p, kpsum_p, kptvx);
    // normalized PV -> yh/yl (overwrites kq region)
    pv_mfma<<<dim3(96, 64), dim3(64), 0, stream>>>(qp, kptvx, yh, yl);
    // out = y @ proj_w^T + proj_b
    gemm_bt_3<<<dim3(6, 256), blk, 0, stream>>>(yh, yl, pwh, pwl, proj_b, out, nullptr, 768, 768, 0);
}

// Round 4
// 675.989 us; speedup vs baseline: 4.9223x; 1.2296x over previous
//
#include <hip/hip_runtime.h>
#include <math.h>

namespace {
constexpr int cB  = 8;
constexpr int cN  = 4096;
constexpr int cC  = 768;
constexpr int cH  = 12;
constexpr int cHD = 64;
constexpr int cM  = 32;
}

typedef __attribute__((ext_vector_type(8))) short bf16x8;
typedef __attribute__((ext_vector_type(4))) float f32x4;

__device__ __forceinline__ void async_copy16(const void* g, void* l) {
    __builtin_amdgcn_global_load_lds((const __attribute__((address_space(1))) void*)g,
                                     (__attribute__((address_space(3))) void*)l, 16, 0, 0);
}

__device__ __forceinline__ ushort f32_to_bf16_rne(float x) {
    unsigned int u = __float_as_uint(x);
    u += 0x7fffu + ((u >> 16) & 1u);
    return (ushort)(u >> 16);
}

__device__ __forceinline__ float bf16_to_f32(ushort u) {
    return __uint_as_float(((unsigned)u) << 16);
}

__device__ __forceinline__ void split2(float f, ushort& h, ushort& l) {
    unsigned u = __float_as_uint(f);
    h = (ushort)(u >> 16);
    float r = f - __uint_as_float(u & 0xffff0000u);
    l = (ushort)(__float_as_uint(r) >> 16);
}

// split fp32 -> bf16 hi (truncate) + bf16 lo (truncate of residual)
__global__ __launch_bounds__(256)
void split_bf16(const float* __restrict__ in, ushort* __restrict__ hi,
                ushort* __restrict__ lo, int n4)
{
    int i = blockIdx.x * 256 + threadIdx.x;
    const int stride = gridDim.x * 256;
    for (; i < n4; i += stride) {
        float4 v = reinterpret_cast<const float4*>(in)[i];
        ushort4 h, l;
        split2(v.x, h.x, l.x);
        split2(v.y, h.y, l.y);
        split2(v.z, h.z, l.z);
        split2(v.w, h.w, l.w);
        reinterpret_cast<ushort4*>(hi)[i] = h;
        reinterpret_cast<ushort4*>(lo)[i] = l;
    }
}

// C[M,N] = (Ah+Al)[M,K]*(Bh+Bl)[N,K]^T + bias, 3-term split fused in one K-loop.
// mode 0: Cf fp32 linear [M,Ndim]; mode 2: Cb bf16, v-permuted [b,h,t,d] layout.
// LDS-read bank-conflict-free via source-side chunk swizzle (rule #21: linear
// gload_lds dest + inverse-swizzled global src + swizzled ds_read).
__global__ __launch_bounds__(256)
void gemm_bt_f(const ushort* __restrict__ Ah, const ushort* __restrict__ Al,
               const ushort* __restrict__ Bh, const ushort* __restrict__ Bl,
               const float* __restrict__ bias,
               float* __restrict__ Cf, ushort* __restrict__ Cb,
               int Ndim, int K, int mode)
{
    __shared__ alignas(16) ushort AsH[128 * 32];
    __shared__ alignas(16) ushort AsL[128 * 32];
    __shared__ alignas(16) ushort BsH[128 * 32];
    __shared__ alignas(16) ushort BsL[128 * 32];
    const int tid = threadIdx.x;
    const int wave = tid >> 6, lane = tid & 63;

    // XCD-chunked block swizzle (nwg divisible by 8 for all grids used here)
    const int nbx = gridDim.x;
    const int nwg = nbx * gridDim.y;
    const int orig = blockIdx.y * nbx + blockIdx.x;
    const int wgid = (orig & 7) * (nwg >> 3) + (orig >> 3);
    const int row0 = (wgid / nbx) * 128;
    const int col0 = (wgid % nbx) * 128;

    const int wm = wave >> 1, wn = wave & 1;
    const int sr = tid >> 2;                        // staging row (0..63)
    const int sk = (((tid & 3) ^ ((sr >> 1) & 3)) * 8); // swizzled k-chunk (ushorts)
    const int fr = lane & 15, fk = lane >> 4;
    const int fco = (fk ^ ((fr >> 1) & 3)) * 8;     // swizzled read chunk (ushorts)
    f32x4 acc[4][4] = {};

    for (int k0 = 0; k0 < K; k0 += 32) {
        const ushort* gah = &Ah[(size_t)(row0 + sr) * K + k0 + sk];
        const ushort* gal = &Al[(size_t)(row0 + sr) * K + k0 + sk];
        const ushort* gbh = &Bh[(size_t)(col0 + sr) * K + k0 + sk];
        const ushort* gbl = &Bl[(size_t)(col0 + sr) * K + k0 + sk];
        async_copy16(gah,            AsH + wave * 512);
        async_copy16(gah + 64 * K,   AsH + 2048 + wave * 512);
        async_copy16(gal,            AsL + wave * 512);
        async_copy16(gal + 64 * K,   AsL + 2048 + wave * 512);
        async_copy16(gbh,            BsH + wave * 512);
        async_copy16(gbh + 64 * K,   BsH + 2048 + wave * 512);
        async_copy16(gbl,            BsL + wave * 512);
        async_copy16(gbl + 64 * K,   BsL + 2048 + wave * 512);
        __syncthreads();   // compiler drains vmcnt(0) before barrier
        bf16x8 ah[4], al[4], bh[4], bl[4];
        #pragma unroll
        for (int mi = 0; mi < 4; ++mi) {
            const int base = (wm * 64 + mi * 16 + fr) * 32 + fco;
            ah[mi] = *reinterpret_cast<const bf16x8*>(&AsH[base]);
            al[mi] = *reinterpret_cast<const bf16x8*>(&AsL[base]);
        }
        #pragma unroll
        for (int ni = 0; ni < 4; ++ni) {
            const int base = (wn * 64 + ni * 16 + fr) * 32 + fco;
            bh[ni] = *reinterpret_cast<const bf16x8*>(&BsH[base]);
            bl[ni] = *reinterpret_cast<const bf16x8*>(&BsL[base]);
        }
        #pragma unroll
        for (int mi = 0; mi < 4; ++mi)
            #pragma unroll
            for (int ni = 0; ni < 4; ++ni) {
                acc[mi][ni] = __builtin_amdgcn_mfma_f32_16x16x32_bf16(ah[mi], bh[ni], acc[mi][ni], 0, 0, 0);
                acc[mi][ni] = __builtin_amdgcn_mfma_f32_16x16x32_bf16(ah[mi], bl[ni], acc[mi][ni], 0, 0, 0);
                acc[mi][ni] = __builtin_amdgcn_mfma_f32_16x16x32_bf16(al[mi], bh[ni], acc[mi][ni], 0, 0, 0);
            }
        __syncthreads();
    }

    const int rbase = row0 + wm * 64 + (lane >> 4) * 4;
    #pragma unroll
    for (int ni = 0; ni < 4; ++ni) {
        const int c = col0 + wn * 64 + ni * 16 + (lane & 15);
        const float bv = bias[c];
        #pragma unroll
        for (int mi = 0; mi < 4; ++mi) {
            const int r = rbase + mi * 16;
            #pragma unroll
            for (int j = 0; j < 4; ++j) {
                const float val = acc[mi][ni][j] + bv;
                const int row = r + j;
                if (mode == 0) {
                    Cf[(size_t)row * Ndim + c] = val;
                } else {
                    const int b = row >> 12, t = row & 4095;
                    const int h = c >> 6, d = c & 63;
                    Cb[(((size_t)(b * cH + h) * cN + t) << 6) + d] = f32_to_bf16_rne(val);
                }
            }
        }
    }
}

// Performer feature map via register-direct MFMA. One wave per (bh, 64-t block).
__global__ __launch_bounds__(64)
void prm_exp_mfma(const float* __restrict__ kq, const ushort* __restrict__ wh,
                  const ushort* __restrict__ wl, ushort* __restrict__ phi,
                  float* __restrict__ kpsum_p, int col_off, int do_sum)
{
    const int bh = blockIdx.x, tblk = blockIdx.y;
    const int b = bh / cH, h = bh % cH;
    const int t0 = tblk * 64;
    const int lane = threadIdx.x;
    const int fr = lane & 15, fk = lane >> 4;

    bf16x8 Bh2[2][2], Bl2[2][2];
    #pragma unroll
    for (int mf = 0; mf < 2; ++mf)
        #pragma unroll
        for (int kc = 0; kc < 2; ++kc) {
            size_t off = (size_t)(h * 32 + mf * 16 + fr) * 64 + kc * 32 + fk * 8;
            Bh2[mf][kc] = *reinterpret_cast<const bf16x8*>(&wh[off]);
            Bl2[mf][kc] = *reinterpret_cast<const bf16x8*>(&wl[off]);
        }

    f32x4 acc[4][2] = {};
    float xdv4[4];
    #pragma unroll
    for (int tf = 0; tf < 4; ++tf) {
        const float* krow = &kq[(size_t)(b * cN + t0 + tf * 16 + fr) * 1536 + col_off + h * 64];
        float4 f0 = *reinterpret_cast<const float4*>(&krow[fk * 8]);
        float4 f1 = *reinterpret_cast<const float4*>(&krow[fk * 8 + 4]);
        float4 f2 = *reinterpret_cast<const float4*>(&krow[32 + fk * 8]);
        float4 f3 = *reinterpret_cast<const float4*>(&krow[32 + fk * 8 + 4]);
        float xs = f0.x*f0.x + f0.y*f0.y + f0.z*f0.z + f0.w*f0.w
                 + f1.x*f1.x + f1.y*f1.y + f1.z*f1.z + f1.w*f1.w
                 + f2.x*f2.x + f2.y*f2.y + f2.z*f2.z + f2.w*f2.w
                 + f3.x*f3.x + f3.y*f3.y + f3.z*f3.z + f3.w*f3.w;
        xs += __shfl_xor(xs, 16);
        xs += __shfl_xor(xs, 32);
        xdv4[tf] = 0.5f * xs;
        bf16x8 Ah2[2], Al2[2];
        {
            float fa[8] = {f0.x,f0.y,f0.z,f0.w,f1.x,f1.y,f1.z,f1.w};
            float fb[8] = {f2.x,f2.y,f2.z,f2.w,f3.x,f3.y,f3.z,f3.w};
            #pragma unroll
            for (int j = 0; j < 8; ++j) {
                ushort hh, ll;
                split2(fa[j], hh, ll); Ah2[0][j] = (short)hh; Al2[0][j] = (short)ll;
                split2(fb[j], hh, ll); Ah2[1][j] = (short)hh; Al2[1][j] = (short)ll;
            }
        }
        #pragma unroll
        for (int kc = 0; kc < 2; ++kc)
            #pragma unroll
            for (int mf = 0; mf < 2; ++mf) {
                acc[tf][mf] = __builtin_amdgcn_mfma_f32_16x16x32_bf16(Ah2[kc], Bh2[mf][kc], acc[tf][mf], 0, 0, 0);
                acc[tf][mf] = __builtin_amdgcn_mfma_f32_16x16x32_bf16(Ah2[kc], Bl2[mf][kc], acc[tf][mf], 0, 0, 0);
                acc[tf][mf] = __builtin_amdgcn_mfma_f32_16x16x32_bf16(Al2[kc], Bh2[mf][kc], acc[tf][mf], 0, 0, 0);
            }
    }

    const float rsm = 0.17677669529663687f;  // 1/sqrt(32)
    float sm0 = 0.f, sm1 = 0.f;
    #pragma unroll
    for (int tf = 0; tf < 4; ++tf) {
        #pragma unroll
        for (int j = 0; j < 4; ++j) {
            const int rloc = (lane >> 4) * 4 + j;
            const float xdv = __shfl(xdv4[tf], (lane & 48) | rloc);
            const int t = t0 + tf * 16 + rloc;
            float e0 = __expf(acc[tf][0][j] - xdv) * rsm;
            float e1 = __expf(acc[tf][1][j] - xdv) * rsm;
            phi[((size_t)bh * cN + t) * cM + fr]      = f32_to_bf16_rne(e0);
            phi[((size_t)bh * cN + t) * cM + 16 + fr] = f32_to_bf16_rne(e1);
            sm0 += e0; sm1 += e1;
        }
    }
    if (do_sum) {
        sm0 += __shfl_xor(sm0, 16); sm0 += __shfl_xor(sm0, 32);
        sm1 += __shfl_xor(sm1, 16); sm1 += __shfl_xor(sm1, 32);
        if (lane < 16) {
            kpsum_p[((size_t)bh * 64 + tblk) * cM + lane]      = sm0;
            kpsum_p[((size_t)bh * 64 + tblk) * cM + 16 + lane] = sm1;
        }
    }
}

// kptv partials: kptv_p[c][bh][d][m] over 32-t slices; c = chunk*2+half, 16 total
__global__ __launch_bounds__(256, 4)
void kptv_part(const ushort* __restrict__ vbf, const ushort* __restrict__ kp,
               float* __restrict__ kptv_p)
{
    const int bh = blockIdx.x, chunk = blockIdx.y;
    __shared__ float vl[64][68];
    __shared__ float kl[64][36];
    const int tid = threadIdx.x;
    const int half = tid >> 7;
    const int dg = (tid >> 3) & 15;
    const int mg = tid & 7;
    float acc[4][4] = {};
    for (int tile = 0; tile < 8; ++tile) {
        const int tb = chunk * 512 + tile * 64;
        #pragma unroll
        for (int i = 0; i < 2; ++i) {
            int idx = i * 256 + tid;
            int row = idx >> 3, seg = idx & 7;
            bf16x8 vv = *reinterpret_cast<const bf16x8*>(&vbf[((size_t)bh * cN + tb + row) * 64 + seg * 8]);
            float4 lo4 = make_float4(bf16_to_f32((ushort)vv[0]), bf16_to_f32((ushort)vv[1]),
                                     bf16_to_f32((ushort)vv[2]), bf16_to_f32((ushort)vv[3]));
            float4 hi4 = make_float4(bf16_to_f32((ushort)vv[4]), bf16_to_f32((ushort)vv[5]),
                                     bf16_to_f32((ushort)vv[6]), bf16_to_f32((ushort)vv[7]));
            *reinterpret_cast<float4*>(&vl[row][seg * 8])     = lo4;
            *reinterpret_cast<float4*>(&vl[row][seg * 8 + 4]) = hi4;
        }
        {
            int row = tid >> 2, seg = tid & 3;
            bf16x8 vv = *reinterpret_cast<const bf16x8*>(&kp[((size_t)bh * cN + tb + row) * 32 + seg * 8]);
            float4 lo4 = make_float4(bf16_to_f32((ushort)vv[0]), bf16_to_f32((ushort)vv[1]),
                                     bf16_to_f32((ushort)vv[2]), bf16_to_f32((ushort)vv[3]));
            float4 hi4 = make_float4(bf16_to_f32((ushort)vv[4]), bf16_to_f32((ushort)vv[5]),
                                     bf16_to_f32((ushort)vv[6]), bf16_to_f32((ushort)vv[7]));
            *reinterpret_cast<float4*>(&kl[row][seg * 8])     = lo4;
            *reinterpret_cast<float4*>(&kl[row][seg * 8 + 4]) = hi4;
        }
        __syncthreads();
        for (int t = 0; t < 32; ++t) {
            const int tt = half * 32 + t;
            float4 av = *reinterpret_cast<const float4*>(&vl[tt][dg * 4]);
            float4 bv = *reinterpret_cast<const float4*>(&kl[tt][mg * 4]);
            float a4[4] = {av.x, av.y, av.z, av.w};
            float b4[4] = {bv.x, bv.y, bv.z, bv.w};
            #pragma unroll
            for (int i = 0; i < 4; ++i)
                #pragma unroll
                for (int j = 0; j < 4; ++j)
                    acc[i][j] = fmaf(a4[i], b4[j], acc[i][j]);
        }
        __syncthreads();
    }
    float* outp = &kptv_p[(((size_t)chunk * 2 + half) * 96 + bh) * 2048];
    #pragma unroll
    for (int i = 0; i < 4; ++i)
        *reinterpret_cast<float4*>(&outp[(dg * 4 + i) * 32 + mg * 4]) =
            make_float4(acc[i][0], acc[i][1], acc[i][2], acc[i][3]);
}

// reduce partials -> kptvx bf16 [bh][80][32]: rows 0..63 kptv, row 64 kpsum, 65..79 zero
__global__ __launch_bounds__(256)
void kptv_reduce(const float* __restrict__ kptv_p, const float* __restrict__ kpsum_p,
                 ushort* __restrict__ kptvx)
{
    const int bh = blockIdx.x, tid = threadIdx.x;
    for (int l = tid; l < 2048; l += 256) {
        float s = 0.f;
        #pragma unroll
        for (int c = 0; c < 16; ++c) s += kptv_p[((size_t)c * 96 + bh) * 2048 + l];
        kptvx[(size_t)bh * 2560 + l] = f32_to_bf16_rne(s);
    }
    if (tid < 32) {
        float s = 0.f;
        #pragma unroll
        for (int c = 0; c < 64; ++c) s += kpsum_p[((size_t)bh * 64 + c) * cM + tid];
        kptvx[(size_t)bh * 2560 + 64 * 32 + tid] = f32_to_bf16_rne(s);
    }
    for (int l = tid; l < 480; l += 256)
        kptvx[(size_t)bh * 2560 + 65 * 32 + l] = 0;
}

// y = (qp . kptv) / (qp . kpsum + eps) via one MFMA pass (D appended as B-row 64)
__global__ __launch_bounds__(64)
void pv_mfma(const ushort* __restrict__ qp, const ushort* __restrict__ kptvx,
             ushort* __restrict__ yh, ushort* __restrict__ yl)
{
    const int bh = blockIdx.x, tblk = blockIdx.y;
    const int b = bh / cH, h = bh % cH;
    const int t0 = tblk * 64;
    const int lane = threadIdx.x;
    const int fr = lane & 15, fk = lane >> 4;
    bf16x8 Bf[5];
    #pragma unroll
    for (int nf = 0; nf < 5; ++nf)
        Bf[nf] = *reinterpret_cast<const bf16x8*>(&kptvx[(size_t)bh * 2560 + (nf * 16 + fr) * 32 + fk * 8]);
    f32x4 acc[4][5] = {};
    #pragma unroll
    for (int tf = 0; tf < 4; ++tf) {
        bf16x8 Af = *reinterpret_cast<const bf16x8*>(&qp[((size_t)bh * cN + t0 + tf * 16 + fr) * cM + fk * 8]);
        #pragma unroll
        for (int nf = 0; nf < 5; ++nf)
            acc[tf][nf] = __builtin_amdgcn_mfma_f32_16x16x32_bf16(Af, Bf[nf], acc[tf][nf], 0, 0, 0);
    }
    #pragma unroll
    for (int tf = 0; tf < 4; ++tf) {
        #pragma unroll
        for (int j = 0; j < 4; ++j) {
            const int rloc = (lane >> 4) * 4 + j;
            const int t = t0 + tf * 16 + rloc;
            const float Dv = __shfl(acc[tf][4][j], lane & 48) + 1e-8f;
            const float rD = 1.0f / Dv;
            #pragma unroll
            for (int nf = 0; nf < 4; ++nf) {
                float yv = acc[tf][nf][j] * rD;
                ushort hh, ll; split2(yv, hh, ll);
                size_t oa = (size_t)(b * cN + t) * cC + h * 64 + nf * 16 + fr;
                yh[oa] = hh; yl[oa] = ll;
            }
        }
    }
}

extern "C" void kernel_launch(void* const* d_in, const int* in_sizes, int n_in,
                              void* d_out, int out_size, void* d_ws, size_t ws_size,
                              hipStream_t stream)
{
    const float* x      = (const float*)d_in[0];
    const float* kqv_w  = (const float*)d_in[1];
    const float* kqv_b  = (const float*)d_in[2];
    const float* proj_w = (const float*)d_in[3];
    const float* proj_b = (const float*)d_in[4];
    const float* w      = (const float*)d_in[5];

    char* wsb = (char*)d_ws;
    float*  kq   = (float*)(wsb);                  // [32768,1536] fp32, 201,326,592 B
    ushort* yh   = (ushort*)(wsb);                 // aliases kq after dead
    ushort* yl   = (ushort*)(wsb + 50331648);
    ushort* vbf  = (ushort*)(wsb + 201326592);     // [96][4096][64] bf16
    ushort* wh   = (ushort*)(wsb + 251658240);     // kqv_w hi
    ushort* wl_  = (ushort*)(wsb + 255197184);     // kqv_w lo
    ushort* pwh  = (ushort*)(wsb + 258736128);     // proj_w hi
    ushort* pwl  = (ushort*)(wsb + 259915776);     // proj_w lo
    ushort* whb  = (ushort*)(wsb + 261095424);     // w hi (bf16)
    ushort* wlb  = (ushort*)(wsb + 261144576);     // w lo

    char* ob = (char*)d_out;
    ushort* xh      = (ushort*)ob;                 // x hi plane
    ushort* xl      = (ushort*)(ob + 50331648);    // x lo plane
    ushort* kp      = (ushort*)ob;                 // [96][4096][32] bf16 (after xh dead)
    ushort* qp      = (ushort*)(ob + 25165824);
    float*  kptv_p  = (float*)(ob + 50331648);     // [16][96][2048] fp32 (after xl dead)
    float*  kpsum_p = (float*)(ob + 62914560);     // [96][64][32] fp32
    ushort* kptvx   = (ushort*)(ob + 63700992);    // [96][80][32] bf16
    float*  out     = (float*)d_out;

    dim3 blk(256);
    // splits
    split_bf16<<<2048, blk, 0, stream>>>(x, xh, xl, 25165824 / 4);
    split_bf16<<<1728, blk, 0, stream>>>(kqv_w, wh, wl_, 1769472 / 4);
    split_bf16<<<576, blk, 0, stream>>>(proj_w, pwh, pwl, 589824 / 4);
    split_bf16<<<24, blk, 0, stream>>>(w, whb, wlb, 24576 / 4);
    // kq = x @ kqv_w[0:1536]^T  (fp32)
    gemm_bt_f<<<dim3(12, 256), blk, 0, stream>>>(xh, xl, wh, wl_, kqv_b, kq, nullptr, 1536, 768, 0);
    // v  = x @ kqv_w[1536:2304]^T  (bf16, [b,h,t,d] layout)
    gemm_bt_f<<<dim3(6, 256), blk, 0, stream>>>(xh, xl, wh + (size_t)1536 * 768, wl_ + (size_t)1536 * 768,
                                                kqv_b + 1536, nullptr, vbf, 768, 768, 2);
    // feature maps (xh/xl dead now; kp/qp overwrite them)
    prm_exp_mfma<<<dim3(96, 64), dim3(64), 0, stream>>>(kq, whb, wlb, kp, kpsum_p, 0, 1);
    prm_exp_mfma<<<dim3(96, 64), dim3(64), 0, stream>>>(kq, whb, wlb, qp, nullptr, 768, 0);
    // kptv partials + reduce (kq dead after prm_exp)
    kptv_part<<<dim3(96, 8), blk, 0, stream>>>(vbf, kp, kptv_p);
    kptv_reduce<<<dim3(96), blk, 0, stream>>>(kptv_p, kpsum_p, kptvx);
    // normalized PV -> yh/yl (overwrites kq region)
    pv_mfma<<<dim3(96, 64), dim3(64), 0, stream>>>(qp, kptvx, yh, yl);
    // out = y @ proj_w^T + proj_b
    gemm_bt_f<<<dim3(6, 256), blk, 0, stream>>>(yh, yl, pwh, pwl, proj_b, out, nullptr, 768, 768, 0);
}

// Round 5
// 599.461 us; speedup vs baseline: 5.5507x; 1.1277x over previous
//
#include <hip/hip_runtime.h>
#include <math.h>

namespace {
constexpr int cB  = 8;
constexpr int cN  = 4096;
constexpr int cC  = 768;
constexpr int cH  = 12;
constexpr int cHD = 64;
constexpr int cM  = 32;
}

typedef __attribute__((ext_vector_type(8))) short bf16x8;
typedef __attribute__((ext_vector_type(4))) float f32x4;

#define BARRIER() do { asm volatile("" ::: "memory"); __builtin_amdgcn_s_barrier(); asm volatile("" ::: "memory"); } while (0)
#define WAIT_LGKM0() do { asm volatile("s_waitcnt lgkmcnt(0)" ::: "memory"); __builtin_amdgcn_sched_barrier(0); } while (0)
#define WAIT_VM0() do { asm volatile("s_waitcnt vmcnt(0)" ::: "memory"); __builtin_amdgcn_sched_barrier(0); } while (0)

__device__ __forceinline__ void async_copy16(const void* g, void* l) {
    __builtin_amdgcn_global_load_lds((const __attribute__((address_space(1))) void*)g,
                                     (__attribute__((address_space(3))) void*)l, 16, 0, 0);
}

__device__ __forceinline__ ushort f32_to_bf16_rne(float x) {
    unsigned int u = __float_as_uint(x);
    u += 0x7fffu + ((u >> 16) & 1u);
    return (ushort)(u >> 16);
}

__device__ __forceinline__ float bf16_to_f32(ushort u) {
    return __uint_as_float(((unsigned)u) << 16);
}

// RNE split: f ~= hi + lo, |residual after hi| <= 2^-9 |f|, unbiased
__device__ __forceinline__ void split2(float f, ushort& h, ushort& l) {
    h = f32_to_bf16_rne(f);
    float r = f - bf16_to_f32(h);
    l = f32_to_bf16_rne(r);
}

__global__ __launch_bounds__(256)
void split_bf16(const float* __restrict__ in, ushort* __restrict__ hi,
                ushort* __restrict__ lo, int n4)
{
    int i = blockIdx.x * 256 + threadIdx.x;
    const int stride = gridDim.x * 256;
    for (; i < n4; i += stride) {
        float4 v = reinterpret_cast<const float4*>(in)[i];
        ushort4 h, l;
        split2(v.x, h.x, l.x);
        split2(v.y, h.y, l.y);
        split2(v.z, h.z, l.z);
        split2(v.w, h.w, l.w);
        reinterpret_cast<ushort4*>(hi)[i] = h;
        reinterpret_cast<ushort4*>(lo)[i] = l;
    }
}

// 256x256-tile, BK=32, 8-wave, dbuf'd 8-phase-style GEMM with counted waits.
// C[M,N] = sum_terms Ap*Bp^T + bias.  TERMS=3: Ah*Bh+Ah*Bl+Al*Bh;  TERMS=1: Ah*Bh.
// mode 0: Cf fp32 [M,Ndim]; mode 2: Cb bf16 v-permuted [b,h,t,d].
// LDS reads bank-conflict-free via the round-4-verified source-side chunk swizzle.
template <int TERMS>
__global__ __launch_bounds__(512, 2)
void gemm256(const ushort* __restrict__ Ah, const ushort* __restrict__ Al,
             const ushort* __restrict__ Bh, const ushort* __restrict__ Bl,
             const float* __restrict__ bias,
             float* __restrict__ Cf, ushort* __restrict__ Cb,
             int Ndim, int K, int mode)
{
    constexpr int NPL = (TERMS == 3) ? 4 : 2;      // planes staged per tile
    __shared__ ushort smem[2 * NPL * 8192];        // dbuf x planes x [256][32]
    const int tid = threadIdx.x;
    const int wave = tid >> 6, lane = tid & 63;
    const int wm = wave >> 2, wn = wave & 3;       // 2M x 4N waves, 128x64 each
    const int fr = lane & 15, fk = lane >> 4;

    // XCD-chunked swizzle, col-major linear id (nrow fixed = 128)
    const int ncol = gridDim.x;
    const int nwg = ncol << 7;
    const int orig = blockIdx.x * 128 + blockIdx.y;
    const int swz = (orig & 7) * (nwg >> 3) + (orig >> 3);
    const int row0 = (swz & 127) << 8;
    const int col0 = (swz >> 7) << 8;

    const ushort* planes[NPL];
    planes[0] = Ah;
    if constexpr (TERMS == 3) { planes[1] = Al; planes[2] = Bh; planes[3] = Bl; }
    else                      { planes[1] = Bh; }

    // per-thread staging descriptors (2 chunk-loads per plane per tile)
    const ushort* gsrc[2 * NPL];
    int ldst[2 * NPL];
    #pragma unroll
    for (int L = 0; L < 2 * NPL; ++L) {
        const int p = L >> 1;
        const int ci = ((L & 1) << 9) + tid;       // chunk index 0..1023
        const int row = ci >> 2;                   // 0..255
        const int cc = (ci & 3) ^ ((row >> 1) & 3);// source-side swizzled chunk
        const int grow = (p < NPL / 2) ? (row0 + row) : (col0 + row);
        gsrc[L] = planes[p] + (size_t)grow * K + cc * 8;
        ldst[L] = (p << 13) + ((L & 1) << 12) + (wave << 9);  // linear LDS dest (ushorts)
    }

    const int NT = K >> 5;
    f32x4 acc[8][4] = {};

    // prologue: stage tile 0 into buf 0, drain, sync
    #pragma unroll
    for (int L = 0; L < 2 * NPL; ++L)
        async_copy16(gsrc[L], &smem[ldst[L]]);
    WAIT_VM0();
    BARRIER();

    for (int t = 0; t < NT; ++t) {
        const int cur = t & 1;
        const int curB = (cur * NPL) << 13;
        const int nxtB = ((cur ^ 1) * NPL) << 13;
        const int kofs = (t + 1) << 5;
        const bool pf = (t + 1 < NT);
        bf16x8 fbh[4], fbl[4];
        #pragma unroll
        for (int ph = 0; ph < 4; ++ph) {
            // ds-reads for this phase (plain loads; lgkmcnt pinned below)
            if (ph == 0) {
                #pragma unroll
                for (int ni = 0; ni < 4; ++ni) {
                    const int brow = wn * 64 + ni * 16 + fr;
                    const int boff = curB + ((NPL / 2) << 13) + brow * 32 + ((fk ^ ((brow >> 1) & 3)) << 3);
                    fbh[ni] = *reinterpret_cast<const bf16x8*>(&smem[boff]);
                    if constexpr (TERMS == 3)
                        fbl[ni] = *reinterpret_cast<const bf16x8*>(&smem[boff + 8192]);
                }
            }
            bf16x8 fah[2], fal[2];
            #pragma unroll
            for (int mm = 0; mm < 2; ++mm) {
                const int arow = wm * 128 + (ph * 2 + mm) * 16 + fr;
                const int aoff = curB + arow * 32 + ((fk ^ ((arow >> 1) & 3)) << 3);
                fah[mm] = *reinterpret_cast<const bf16x8*>(&smem[aoff]);
                if constexpr (TERMS == 3)
                    fal[mm] = *reinterpret_cast<const bf16x8*>(&smem[aoff + 8192]);
            }
            // prefetch next tile early (phases 0-1) -> latency covered by phases 1-3
            if (ph == 0 && pf) {
                #pragma unroll
                for (int L = 0; L < NPL; ++L)
                    async_copy16(gsrc[L] + kofs, &smem[nxtB + ldst[L]]);
            }
            if (ph == 1 && pf) {
                #pragma unroll
                for (int L = NPL; L < 2 * NPL; ++L)
                    async_copy16(gsrc[L] + kofs, &smem[nxtB + ldst[L]]);
            }
            BARRIER();
            WAIT_LGKM0();
            __builtin_amdgcn_s_setprio(1);
            #pragma unroll
            for (int mm = 0; mm < 2; ++mm)
                #pragma unroll
                for (int ni = 0; ni < 4; ++ni)
                    acc[ph * 2 + mm][ni] = __builtin_amdgcn_mfma_f32_16x16x32_bf16(fah[mm], fbh[ni], acc[ph * 2 + mm][ni], 0, 0, 0);
            if constexpr (TERMS == 3) {
                #pragma unroll
                for (int mm = 0; mm < 2; ++mm)
                    #pragma unroll
                    for (int ni = 0; ni < 4; ++ni)
                        acc[ph * 2 + mm][ni] = __builtin_amdgcn_mfma_f32_16x16x32_bf16(fah[mm], fbl[ni], acc[ph * 2 + mm][ni], 0, 0, 0);
                #pragma unroll
                for (int mm = 0; mm < 2; ++mm)
                    #pragma unroll
                    for (int ni = 0; ni < 4; ++ni)
                        acc[ph * 2 + mm][ni] = __builtin_amdgcn_mfma_f32_16x16x32_bf16(fal[mm], fbh[ni], acc[ph * 2 + mm][ni], 0, 0, 0);
            }
            __builtin_amdgcn_s_setprio(0);
            if (ph == 3) WAIT_VM0();   // tile t+1's loads landed; buf swap safe
            BARRIER();
        }
    }

    #pragma unroll
    for (int ni = 0; ni < 4; ++ni) {
        const int c = col0 + wn * 64 + ni * 16 + fr;
        const float bv = bias[c];
        #pragma unroll
        for (int mi = 0; mi < 8; ++mi) {
            const int r0 = row0 + wm * 128 + mi * 16 + (lane >> 4) * 4;
            #pragma unroll
            for (int j = 0; j < 4; ++j) {
                const float val = acc[mi][ni][j] + bv;
                const int row = r0 + j;
                if (mode == 0) {
                    Cf[(size_t)row * Ndim + c] = val;
                } else {
                    const int b = row >> 12, tt = row & 4095;
                    const int h = c >> 6, d = c & 63;
                    Cb[(((size_t)(b * cH + h) * cN + tt) << 6) + d] = f32_to_bf16_rne(val);
                }
            }
        }
    }
}

// Performer feature map via register-direct MFMA. One wave per (bh, 64-t block).
__global__ __launch_bounds__(64)
void prm_exp_mfma(const float* __restrict__ kq, const ushort* __restrict__ wh,
                  const ushort* __restrict__ wl, ushort* __restrict__ phi,
                  float* __restrict__ kpsum_p, int col_off, int do_sum)
{
    const int bh = blockIdx.x, tblk = blockIdx.y;
    const int b = bh / cH, h = bh % cH;
    const int t0 = tblk * 64;
    const int lane = threadIdx.x;
    const int fr = lane & 15, fk = lane >> 4;

    bf16x8 Bh2[2][2], Bl2[2][2];
    #pragma unroll
    for (int mf = 0; mf < 2; ++mf)
        #pragma unroll
        for (int kc = 0; kc < 2; ++kc) {
            size_t off = (size_t)(h * 32 + mf * 16 + fr) * 64 + kc * 32 + fk * 8;
            Bh2[mf][kc] = *reinterpret_cast<const bf16x8*>(&wh[off]);
            Bl2[mf][kc] = *reinterpret_cast<const bf16x8*>(&wl[off]);
        }

    f32x4 acc[4][2] = {};
    float xdv4[4];
    #pragma unroll
    for (int tf = 0; tf < 4; ++tf) {
        const float* krow = &kq[(size_t)(b * cN + t0 + tf * 16 + fr) * 1536 + col_off + h * 64];
        float4 f0 = *reinterpret_cast<const float4*>(&krow[fk * 8]);
        float4 f1 = *reinterpret_cast<const float4*>(&krow[fk * 8 + 4]);
        float4 f2 = *reinterpret_cast<const float4*>(&krow[32 + fk * 8]);
        float4 f3 = *reinterpret_cast<const float4*>(&krow[32 + fk * 8 + 4]);
        float xs = f0.x*f0.x + f0.y*f0.y + f0.z*f0.z + f0.w*f0.w
                 + f1.x*f1.x + f1.y*f1.y + f1.z*f1.z + f1.w*f1.w
                 + f2.x*f2.x + f2.y*f2.y + f2.z*f2.z + f2.w*f2.w
                 + f3.x*f3.x + f3.y*f3.y + f3.z*f3.z + f3.w*f3.w;
        xs += __shfl_xor(xs, 16);
        xs += __shfl_xor(xs, 32);
        xdv4[tf] = 0.5f * xs;
        bf16x8 Ah2[2], Al2[2];
        {
            float fa[8] = {f0.x,f0.y,f0.z,f0.w,f1.x,f1.y,f1.z,f1.w};
            float fb[8] = {f2.x,f2.y,f2.z,f2.w,f3.x,f3.y,f3.z,f3.w};
            #pragma unroll
            for (int j = 0; j < 8; ++j) {
                ushort hh, ll;
                split2(fa[j], hh, ll); Ah2[0][j] = (short)hh; Al2[0][j] = (short)ll;
                split2(fb[j], hh, ll); Ah2[1][j] = (short)hh; Al2[1][j] = (short)ll;
            }
        }
        #pragma unroll
        for (int kc = 0; kc < 2; ++kc)
            #pragma unroll
            for (int mf = 0; mf < 2; ++mf) {
                acc[tf][mf] = __builtin_amdgcn_mfma_f32_16x16x32_bf16(Ah2[kc], Bh2[mf][kc], acc[tf][mf], 0, 0, 0);
                acc[tf][mf] = __builtin_amdgcn_mfma_f32_16x16x32_bf16(Ah2[kc], Bl2[mf][kc], acc[tf][mf], 0, 0, 0);
                acc[tf][mf] = __builtin_amdgcn_mfma_f32_16x16x32_bf16(Al2[kc], Bh2[mf][kc], acc[tf][mf], 0, 0, 0);
            }
    }

    const float rsm = 0.17677669529663687f;  // 1/sqrt(32)
    float sm0 = 0.f, sm1 = 0.f;
    #pragma unroll
    for (int tf = 0; tf < 4; ++tf) {
        #pragma unroll
        for (int j = 0; j < 4; ++j) {
            const int rloc = (lane >> 4) * 4 + j;
            const float xdv = __shfl(xdv4[tf], (lane & 48) | rloc);
            const int t = t0 + tf * 16 + rloc;
            float e0 = __expf(acc[tf][0][j] - xdv) * rsm;
            float e1 = __expf(acc[tf][1][j] - xdv) * rsm;
            phi[((size_t)bh * cN + t) * cM + fr]      = f32_to_bf16_rne(e0);
            phi[((size_t)bh * cN + t) * cM + 16 + fr] = f32_to_bf16_rne(e1);
            sm0 += e0; sm1 += e1;
        }
    }
    if (do_sum) {
        sm0 += __shfl_xor(sm0, 16); sm0 += __shfl_xor(sm0, 32);
        sm1 += __shfl_xor(sm1, 16); sm1 += __shfl_xor(sm1, 32);
        if (lane < 16) {
            kpsum_p[((size_t)bh * 64 + tblk) * cM + lane]      = sm0;
            kpsum_p[((size_t)bh * 64 + tblk) * cM + 16 + lane] = sm1;
        }
    }
}

// kptv partials: kptv_p[c][bh][d][m] over 32-t slices; c = chunk*2+half, 16 total
__global__ __launch_bounds__(256, 4)
void kptv_part(const ushort* __restrict__ vbf, const ushort* __restrict__ kp,
               float* __restrict__ kptv_p)
{
    const int bh = blockIdx.x, chunk = blockIdx.y;
    __shared__ float vl[64][68];
    __shared__ float kl[64][36];
    const int tid = threadIdx.x;
    const int half = tid >> 7;
    const int dg = (tid >> 3) & 15;
    const int mg = tid & 7;
    float acc[4][4] = {};
    for (int tile = 0; tile < 8; ++tile) {
        const int tb = chunk * 512 + tile * 64;
        #pragma unroll
        for (int i = 0; i < 2; ++i) {
            int idx = i * 256 + tid;
            int row = idx >> 3, seg = idx & 7;
            bf16x8 vv = *reinterpret_cast<const bf16x8*>(&vbf[((size_t)bh * cN + tb + row) * 64 + seg * 8]);
            float4 lo4 = make_float4(bf16_to_f32((ushort)vv[0]), bf16_to_f32((ushort)vv[1]),
                                     bf16_to_f32((ushort)vv[2]), bf16_to_f32((ushort)vv[3]));
            float4 hi4 = make_float4(bf16_to_f32((ushort)vv[4]), bf16_to_f32((ushort)vv[5]),
                                     bf16_to_f32((ushort)vv[6]), bf16_to_f32((ushort)vv[7]));
            *reinterpret_cast<float4*>(&vl[row][seg * 8])     = lo4;
            *reinterpret_cast<float4*>(&vl[row][seg * 8 + 4]) = hi4;
        }
        {
            int row = tid >> 2, seg = tid & 3;
            bf16x8 vv = *reinterpret_cast<const bf16x8*>(&kp[((size_t)bh * cN + tb + row) * 32 + seg * 8]);
            float4 lo4 = make_float4(bf16_to_f32((ushort)vv[0]), bf16_to_f32((ushort)vv[1]),
                                     bf16_to_f32((ushort)vv[2]), bf16_to_f32((ushort)vv[3]));
            float4 hi4 = make_float4(bf16_to_f32((ushort)vv[4]), bf16_to_f32((ushort)vv[5]),
                                     bf16_to_f32((ushort)vv[6]), bf16_to_f32((ushort)vv[7]));
            *reinterpret_cast<float4*>(&kl[row][seg * 8])     = lo4;
            *reinterpret_cast<float4*>(&kl[row][seg * 8 + 4]) = hi4;
        }
        __syncthreads();
        for (int t = 0; t < 32; ++t) {
            const int tt = half * 32 + t;
            float4 av = *reinterpret_cast<const float4*>(&vl[tt][dg * 4]);
            float4 bv = *reinterpret_cast<const float4*>(&kl[tt][mg * 4]);
            float a4[4] = {av.x, av.y, av.z, av.w};
            float b4[4] = {bv.x, bv.y, bv.z, bv.w};
            #pragma unroll
            for (int i = 0; i < 4; ++i)
                #pragma unroll
                for (int j = 0; j < 4; ++j)
                    acc[i][j] = fmaf(a4[i], b4[j], acc[i][j]);
        }
        __syncthreads();
    }
    float* outp = &kptv_p[(((size_t)chunk * 2 + half) * 96 + bh) * 2048];
    #pragma unroll
    for (int i = 0; i < 4; ++i)
        *reinterpret_cast<float4*>(&outp[(dg * 4 + i) * 32 + mg * 4]) =
            make_float4(acc[i][0], acc[i][1], acc[i][2], acc[i][3]);
}

// reduce partials -> kptvx bf16 [bh][80][32]: rows 0..63 kptv, row 64 kpsum, 65..79 zero
__global__ __launch_bounds__(256)
void kptv_reduce(const float* __restrict__ kptv_p, const float* __restrict__ kpsum_p,
                 ushort* __restrict__ kptvx)
{
    const int bh = blockIdx.x, tid = threadIdx.x;
    for (int l = tid; l < 2048; l += 256) {
        float s = 0.f;
        #pragma unroll
        for (int c = 0; c < 16; ++c) s += kptv_p[((size_t)c * 96 + bh) * 2048 + l];
        kptvx[(size_t)bh * 2560 + l] = f32_to_bf16_rne(s);
    }
    if (tid < 32) {
        float s = 0.f;
        #pragma unroll
        for (int c = 0; c < 64; ++c) s += kpsum_p[((size_t)bh * 64 + c) * cM + tid];
        kptvx[(size_t)bh * 2560 + 64 * 32 + tid] = f32_to_bf16_rne(s);
    }
    for (int l = tid; l < 480; l += 256)
        kptvx[(size_t)bh * 2560 + 65 * 32 + l] = 0;
}

// y = (qp . kptv) / (qp . kpsum + eps) via one MFMA pass (D appended as B-row 64)
__global__ __launch_bounds__(64)
void pv_mfma(const ushort* __restrict__ qp, const ushort* __restrict__ kptvx,
             ushort* __restrict__ yh, ushort* __restrict__ yl)
{
    const int bh = blockIdx.x, tblk = blockIdx.y;
    const int b = bh / cH, h = bh % cH;
    const int t0 = tblk * 64;
    const int lane = threadIdx.x;
    const int fr = lane & 15, fk = lane >> 4;
    bf16x8 Bf[5];
    #pragma unroll
    for (int nf = 0; nf < 5; ++nf)
        Bf[nf] = *reinterpret_cast<const bf16x8*>(&kptvx[(size_t)bh * 2560 + (nf * 16 + fr) * 32 + fk * 8]);
    f32x4 acc[4][5] = {};
    #pragma unroll
    for (int tf = 0; tf < 4; ++tf) {
        bf16x8 Af = *reinterpret_cast<const bf16x8*>(&qp[((size_t)bh * cN + t0 + tf * 16 + fr) * cM + fk * 8]);
        #pragma unroll
        for (int nf = 0; nf < 5; ++nf)
            acc[tf][nf] = __builtin_amdgcn_mfma_f32_16x16x32_bf16(Af, Bf[nf], acc[tf][nf], 0, 0, 0);
    }
    #pragma unroll
    for (int tf = 0; tf < 4; ++tf) {
        #pragma unroll
        for (int j = 0; j < 4; ++j) {
            const int rloc = (lane >> 4) * 4 + j;
            const int t = t0 + tf * 16 + rloc;
            const float Dv = __shfl(acc[tf][4][j], lane & 48) + 1e-8f;
            const float rD = 1.0f / Dv;
            #pragma unroll
            for (int nf = 0; nf < 4; ++nf) {
                float yv = acc[tf][nf][j] * rD;
                ushort hh, ll; split2(yv, hh, ll);
                size_t oa = (size_t)(b * cN + t) * cC + h * 64 + nf * 16 + fr;
                yh[oa] = hh; yl[oa] = ll;
            }
        }
    }
}

extern "C" void kernel_launch(void* const* d_in, const int* in_sizes, int n_in,
                              void* d_out, int out_size, void* d_ws, size_t ws_size,
                              hipStream_t stream)
{
    const float* x      = (const float*)d_in[0];
    const float* kqv_w  = (const float*)d_in[1];
    const float* kqv_b  = (const float*)d_in[2];
    const float* proj_w = (const float*)d_in[3];
    const float* proj_b = (const float*)d_in[4];
    const float* w      = (const float*)d_in[5];

    char* wsb = (char*)d_ws;
    float*  kq   = (float*)(wsb);                  // [32768,1536] fp32, 201,326,592 B
    ushort* yh   = (ushort*)(wsb);                 // aliases kq after dead
    ushort* yl   = (ushort*)(wsb + 50331648);
    ushort* vbf  = (ushort*)(wsb + 201326592);     // [96][4096][64] bf16
    ushort* wh   = (ushort*)(wsb + 251658240);     // kqv_w hi
    ushort* wl_  = (ushort*)(wsb + 255197184);     // kqv_w lo
    ushort* pwh  = (ushort*)(wsb + 258736128);     // proj_w hi
    ushort* pwl  = (ushort*)(wsb + 259915776);     // proj_w lo
    ushort* whb  = (ushort*)(wsb + 261095424);     // w hi (bf16)
    ushort* wlb  = (ushort*)(wsb + 261144576);     // w lo

    char* ob = (char*)d_out;
    ushort* xh      = (ushort*)ob;                 // x hi plane
    ushort* xl      = (ushort*)(ob + 50331648);    // x lo plane
    ushort* kp      = (ushort*)ob;                 // [96][4096][32] bf16 (after xh dead)
    ushort* qp      = (ushort*)(ob + 25165824);
    float*  kptv_p  = (float*)(ob + 50331648);     // [16][96][2048] fp32 (after xl dead)
    float*  kpsum_p = (float*)(ob + 62914560);     // [96][64][32] fp32
    ushort* kptvx   = (ushort*)(ob + 63700992);    // [96][80][32] bf16
    float*  out     = (float*)d_out;

    dim3 blk(256);
    // splits (RNE hi/lo planes)
    split_bf16<<<2048, blk, 0, stream>>>(x, xh, xl, 25165824 / 4);
    split_bf16<<<1728, blk, 0, stream>>>(kqv_w, wh, wl_, 1769472 / 4);
    split_bf16<<<576, blk, 0, stream>>>(proj_w, pwh, pwl, 589824 / 4);
    split_bf16<<<24, blk, 0, stream>>>(w, whb, wlb, 24576 / 4);
    // kq = x @ kqv_w[0:1536]^T  (fp32, 3-term)
    gemm256<3><<<dim3(6, 128), dim3(512), 0, stream>>>(xh, xl, wh, wl_, kqv_b, kq, nullptr, 1536, 768, 0);
    // v  = x @ kqv_w[1536:2304]^T  (bf16 out, 1-term: output rounding dominates)
    gemm256<1><<<dim3(3, 128), dim3(512), 0, stream>>>(xh, nullptr, wh + (size_t)1536 * 768, nullptr,
                                                       kqv_b + 1536, nullptr, vbf, 768, 768, 2);
    // feature maps (xh/xl dead now; kp/qp overwrite them)
    prm_exp_mfma<<<dim3(96, 64), dim3(64), 0, stream>>>(kq, whb, wlb, kp, kpsum_p, 0, 1);
    prm_exp_mfma<<<dim3(96, 64), dim3(64), 0, stream>>>(kq, whb, wlb, qp, nullptr, 768, 0);
    // kptv partials + reduce (kq dead after prm_exp)
    kptv_part<<<dim3(96, 8), blk, 0, stream>>>(vbf, kp, kptv_p);
    kptv_reduce<<<dim3(96), blk, 0, stream>>>(kptv_p, kpsum_p, kptvx);
    // normalized PV -> yh/yl (overwrites kq region)
    pv_mfma<<<dim3(96, 64), dim3(64), 0, stream>>>(qp, kptvx, yh, yl);
    // out = y @ proj_w^T + proj_b  (3-term)
    gemm256<3><<<dim3(3, 128), dim3(512), 0, stream>>>(yh, yl, pwh, pwl, proj_b, out, nullptr, 768, 768, 0);
}